// Round 1
// baseline (165.120 us; speedup 1.0000x reference)
//
#include <hip/hip_runtime.h>
#include <math.h>

// HadamardProj: out[b,o] = -scale * (x[b]/(||x[b]||+eps)) . H[o,:] + bias[o]
// H[o,i] = (-1)^popcount(o&i), i<2048  =>  H row o == H row (o mod 2048)
// => y[b] = FWHT_2048(x[b]) (Sylvester order), out[b,o] = -scale*inv_norm*y[o&2047] + bias[o]

constexpr int N_IN  = 2048;    // input dim (2^11)
constexpr int N_OUT = 10000;   // output dim
constexpr int ROWS_PER_BLOCK = 4;  // one wave64 per row, 256 threads/block

__global__ __launch_bounds__(256, 5) void fwht_proj_kernel(
    const float* __restrict__ x,
    const float* __restrict__ scale,
    const float* __restrict__ bias,
    float* __restrict__ out)
{
    __shared__ float lds[ROWS_PER_BLOCK * N_IN];   // 32 KiB: 8 KiB per wave

    const int wave = threadIdx.x >> 6;
    const int lane = threadIdx.x & 63;
    const int row  = (blockIdx.x << 2) + wave;     // grid = rows/4, rows % 4 == 0

    const float* __restrict__ xrow = x + (size_t)row * N_IN;

    // Thread `lane` owns elements e = lane + 64*j  (coalesced loads)
    float v[32];
    float ss = 0.0f;
#pragma unroll
    for (int j = 0; j < 32; ++j) {
        v[j] = xrow[j * 64 + lane];
        ss = fmaf(v[j], v[j], ss);
    }
    // wave-wide sum of squares
#pragma unroll
    for (int m = 1; m < 64; m <<= 1)
        ss += __shfl_xor(ss, m, 64);
    const float inv = 1.0f / (sqrtf(ss) + 1e-8f);  // matches x/(norm+eps)

    // FWHT stages commute (tensor-factor structure), so order is free.
    // Cross-lane stages: element stride h = 1..32  ->  lane xor mask h
#pragma unroll
    for (int m = 1; m <= 32; m <<= 1) {
        const bool lo = (lane & m) == 0;
#pragma unroll
        for (int j = 0; j < 32; ++j) {
            float o = __shfl_xor(v[j], m, 64);
            v[j] = lo ? (v[j] + o) : (o - v[j]);
        }
    }
    // In-register stages: element stride h = 64..1024 -> register xor 1..16
#pragma unroll
    for (int jm = 1; jm <= 16; jm <<= 1) {
#pragma unroll
        for (int j = 0; j < 32; ++j) {
            if ((j & jm) == 0) {
                const float a = v[j], b = v[j ^ jm];
                v[j]      = a + b;
                v[j ^ jm] = a - b;
            }
        }
    }

    // Stage y into this wave's private LDS segment (stride-64 writes: conflict-free)
    float* __restrict__ my = lds + wave * N_IN;
#pragma unroll
    for (int j = 0; j < 32; ++j)
        my[j * 64 + lane] = v[j];

    __syncthreads();   // orders LDS writes vs. reads (cheap: one per row)

    const float s = -scale[0] * inv;   // fold norm + negated scale into one FMA coeff
    float* __restrict__ orow = out + (size_t)row * N_OUT;

    // 2500 float4 stores per row, coalesced; y reads linear in LDS (conflict-free).
    // o is 4-aligned and 2048-windows are 4-aligned, so (o&2047)+3 never wraps.
    for (int idx = lane; idx < N_OUT / 4; idx += 64) {
        const int o = idx << 2;
        const float4 y  = *reinterpret_cast<const float4*>(my + (o & (N_IN - 1)));
        const float4 bv = *reinterpret_cast<const float4*>(bias + o);
        float4 r;
        r.x = fmaf(s, y.x, bv.x);
        r.y = fmaf(s, y.y, bv.y);
        r.z = fmaf(s, y.z, bv.z);
        r.w = fmaf(s, y.w, bv.w);
        *reinterpret_cast<float4*>(orow + o) = r;
    }
}

extern "C" void kernel_launch(void* const* d_in, const int* in_sizes, int n_in,
                              void* d_out, int out_size, void* d_ws, size_t ws_size,
                              hipStream_t stream) {
    const float* x     = (const float*)d_in[0];
    // d_in[1] = proj: unused — Hadamard structure computed via FWHT instead
    const float* scale = (const float*)d_in[2];
    const float* bias  = (const float*)d_in[3];
    float* out = (float*)d_out;

    const int rows = in_sizes[0] / N_IN;            // 16384
    dim3 grid(rows / ROWS_PER_BLOCK), block(256);
    hipLaunchKernelGGL(fwht_proj_kernel, grid, block, 0, stream,
                       x, scale, bias, out);
}